// Round 6
// baseline (184.102 us; speedup 1.0000x reference)
//
#include <hip/hip_runtime.h>
#include <math.h>
#include <float.h>

// DeepSeek V3 router, round 6.
// Split-fp16 MFMA GEMM (3 passes: X0W0 + 2^-11(X1W0 + X0W1)).
// R6: triple-buffered B with 2-deep global_load_lds prefetch + counted vmcnt
// (DMAs stay in flight across barriers), raw s_barrier (no vmcnt(0) drain),
// MFMA pass-reordered (16-instr gap between dependent accumulators),
// s_setprio around the MFMA cluster. Numerics identical to R3-R5.

#define TDIM 8192
#define DDIM 7168
#define EDIM 256

typedef _Float16 h8 __attribute__((ext_vector_type(8)));
typedef _Float16 h4 __attribute__((ext_vector_type(4)));
typedef float f4 __attribute__((ext_vector_type(4)));

typedef const __attribute__((address_space(1))) void* gas_t;
typedef __attribute__((address_space(3))) void* las_t;

// ---------------- K1: W -> 2 transposed fp16 planes [E][K] ----------------
__global__ __launch_bounds__(256)
void convert_w(const float* __restrict__ W,
               _Float16* __restrict__ Wt0, _Float16* __restrict__ Wt1)
{
    __shared__ _Float16 l0[64][80];
    __shared__ _Float16 l1[64][80];
    const int t = threadIdx.x;
    const int kt = blockIdx.x * 64;
    const int et = blockIdx.y * 64;
#pragma unroll
    for (int i = 0; i < 16; ++i) {
        const int kr = (t >> 6) * 16 + i;
        const int ec = t & 63;
        const float w = W[(size_t)(kt + kr) * EDIM + et + ec] * 256.f;
        const _Float16 h0 = (_Float16)w;
        const _Float16 h1 = (_Float16)((w - (float)h0) * 2048.f);
        l0[ec][kr] = h0;
        l1[ec][kr] = h1;
    }
    __syncthreads();
#pragma unroll
    for (int j = 0; j < 2; ++j) {
        const int er = t >> 2;
        const int kc = ((t & 3) + 4 * j) * 8;
        const uint4 v0 = *(const uint4*)&l0[er][kc];
        const uint4 v1 = *(const uint4*)&l1[er][kc];
        *(uint4*)&Wt0[(size_t)(et + er) * DDIM + kt + kc] = v0;
        *(uint4*)&Wt1[(size_t)(et + er) * DDIM + kt + kc] = v1;
    }
}

// ---------------- K2: split-fp16 MFMA GEMM ----------------
// LDS: 16B slot s of row r holds original granule s ^ ((r>>2)&3).
__global__ __launch_bounds__(256, 2)
void gemm_mfma(const float* __restrict__ X,
               const _Float16* __restrict__ Wt0,
               const _Float16* __restrict__ Wt1,
               float* __restrict__ P,
               int splitK, int kLen)
{
    __shared__ _Float16 sA[2][2][128][32];  // 32 KB (A double-buffer)
    __shared__ _Float16 sB[3][2][128][32];  // 48 KB (B triple-buffer)

    const int t    = threadIdx.x;
    const int lane = t & 63;
    const int wid  = t >> 6;

    const int cpx = gridDim.x >> 3;
    const int L   = (blockIdx.x & 7) * cpx + (blockIdx.x >> 3);
    const int nb  = L & 1;
    const int r1  = L >> 1;
    const int ks  = r1 % splitK;
    const int mb  = r1 / splitK;
    const int m0  = mb * 128;
    const int e0  = nb * 128;
    const int kbeg = ks * kLen;
    const int ntiles = kLen >> 5;

    f4 acc0[4][4], acc1[4][4];
#pragma unroll
    for (int i = 0; i < 4; ++i)
#pragma unroll
        for (int j = 0; j < 4; ++j) { acc0[i][j] = (f4)0.f; acc1[i][j] = (f4)0.f; }

    const float* xg = X + (size_t)(m0 + (t >> 3)) * DDIM + kbeg + (t & 7) * 4;
    const int rowA = t >> 3;
    const int colA = (((((t & 7) >> 1) ^ ((t >> 5) & 3)) & 3) << 3)
                   | ((t & 1) << 2);

    const _Float16* bsrc[4];
    {
        const int gsw = (((lane & 3) ^ ((lane >> 4) & 3)) & 3) * 8;
        const _Float16* wp = (wid >> 1) ? Wt1 : Wt0;
#pragma unroll
        for (int i = 0; i < 4; ++i) {
            const int br = ((wid & 1) * 4 + i) * 16;
            bsrc[i] = wp + (size_t)(e0 + br + (lane >> 2)) * DDIM + kbeg + gsw;
        }
    }

    float4 va[4];

#define DMAB(buf, kb)                                                         \
    {                                                                         \
        _Pragma("unroll")                                                     \
        for (int i = 0; i < 4; ++i)                                           \
            __builtin_amdgcn_global_load_lds(                                 \
                (gas_t)(bsrc[i] + (kb)),                                      \
                (las_t)&sB[buf][wid >> 1][((wid & 1) * 4 + i) * 16][0],       \
                16, 0, 0);                                                    \
    }

#define LOADA(kb)                                                             \
    {                                                                         \
        _Pragma("unroll")                                                     \
        for (int p = 0; p < 4; ++p)                                           \
            va[p] = *(const float4*)(xg + (size_t)p * 32 * DDIM + (kb));      \
    }

#define WRITEA(buf)                                                           \
    {                                                                         \
        _Pragma("unroll")                                                     \
        for (int p = 0; p < 4; ++p) {                                         \
            h4 p0, p1;                                                        \
            const float xv[4] = {va[p].x, va[p].y, va[p].z, va[p].w};         \
            _Pragma("unroll")                                                 \
            for (int j = 0; j < 4; ++j) {                                     \
                const _Float16 h0 = (_Float16)xv[j];                          \
                p0[j] = h0;                                                   \
                p1[j] = (_Float16)((xv[j] - (float)h0) * 2048.f);             \
            }                                                                 \
            *(h4*)&sA[buf][0][rowA + 32 * p][colA] = p0;                      \
            *(h4*)&sA[buf][1][rowA + 32 * p][colA] = p1;                      \
        }                                                                     \
    }

    // prologue: A(tile0) via regs; B tiles 0,1 via DMA (stay counted)
    LOADA(0);
    DMAB(0, 0);
    if (ntiles > 1) DMAB(1, 32);
    WRITEA(0);                         // compiler waits va (vmcnt(8))
    asm volatile("s_waitcnt lgkmcnt(0)" ::: "memory");
    __builtin_amdgcn_s_barrier();

    const int fr  = (wid >> 1) * 64 + (lane & 15);
    const int fc  = (wid & 1) * 64 + (lane & 15);
    const int kqs = (((lane >> 4) ^ (lane >> 2)) & 3) << 3;

    int bc = 0;      // current B buffer
    int ca = 0;      // current A buffer

    for (int tile = 0; tile < ntiles; ++tile) {
        // ensure B(cur) DMA drained (steady state: no-op, 4 newest remain)
        asm volatile("s_waitcnt vmcnt(4)" ::: "memory");
        __builtin_amdgcn_sched_barrier(0);

        const bool hn  = (tile + 1) < ntiles;
        const bool hn2 = (tile + 2) < ntiles;
        if (hn) LOADA((tile + 1) * 32);
        if (hn2) {
            const int b2 = (bc == 0) ? 2 : bc - 1;   // (bc+2)%3
            DMAB(b2, (tile + 2) * 32);
        }
        __builtin_amdgcn_sched_barrier(0);

        h8 a0[4], a1[4], b0[4], b1[4];
#pragma unroll
        for (int f = 0; f < 4; ++f) {
            a0[f] = *(const h8*)&sA[ca][0][fr + f * 16][kqs];
            a1[f] = *(const h8*)&sA[ca][1][fr + f * 16][kqs];
            b0[f] = *(const h8*)&sB[bc][0][fc + f * 16][kqs];
            b1[f] = *(const h8*)&sB[bc][1][fc + f * 16][kqs];
        }

        __builtin_amdgcn_s_setprio(1);
#pragma unroll
        for (int fm = 0; fm < 4; ++fm)
#pragma unroll
            for (int fn = 0; fn < 4; ++fn)
                acc0[fm][fn] = __builtin_amdgcn_mfma_f32_16x16x32_f16(
                    a0[fm], b0[fn], acc0[fm][fn], 0, 0, 0);
#pragma unroll
        for (int fm = 0; fm < 4; ++fm)
#pragma unroll
            for (int fn = 0; fn < 4; ++fn)
                acc1[fm][fn] = __builtin_amdgcn_mfma_f32_16x16x32_f16(
                    a1[fm], b0[fn], acc1[fm][fn], 0, 0, 0);
#pragma unroll
        for (int fm = 0; fm < 4; ++fm)
#pragma unroll
            for (int fn = 0; fn < 4; ++fn)
                acc1[fm][fn] = __builtin_amdgcn_mfma_f32_16x16x32_f16(
                    a0[fm], b1[fn], acc1[fm][fn], 0, 0, 0);
        __builtin_amdgcn_s_setprio(0);

        if (hn) WRITEA(ca ^ 1);        // compiler waits va (vmcnt(4): leaves
                                       // the 2-ahead DMAs in flight)
        asm volatile("s_waitcnt lgkmcnt(0)" ::: "memory");
        __builtin_amdgcn_s_barrier();

        bc = (bc == 2) ? 0 : bc + 1;
        ca ^= 1;
    }

    const float s0 = 1.f / 256.f, s1 = 1.f / 524288.f;
#pragma unroll
    for (int fm = 0; fm < 4; ++fm)
#pragma unroll
        for (int fn = 0; fn < 4; ++fn) {
            const int gr = m0 + (wid >> 1) * 64 + fm * 16 + (lane >> 4) * 4;
            const int gc = e0 + (wid & 1) * 64 + fn * 16 + (lane & 15);
#pragma unroll
            for (int r = 0; r < 4; ++r) {
                const float v = acc0[fm][fn][r] * s0 + acc1[fm][fn][r] * s1;
                P[((size_t)ks * TDIM + gr + r) * EDIM + gc] = v;
            }
        }
}

// ---------------- K3: reduce + sigmoid + grouped top-k route ----------------
__global__ __launch_bounds__(256, 4)
void route_kernel(const float* __restrict__ P,
                  const float* __restrict__ B,
                  float* __restrict__ out,
                  int splitK)
{
    const int t    = threadIdx.x;
    const int lane = t & 63;
    const int wid  = t >> 6;
    const int tok0 = blockIdx.x * 32 + wid * 8;

    const float4 bv4 = *(const float4*)&B[lane * 4];
    const float bb[4] = {bv4.x, bv4.y, bv4.z, bv4.w};
    const int g = lane >> 3;

#pragma unroll
    for (int i = 0; i < 8; ++i) {
        const int tok = tok0 + i;
        float a[4] = {0.f, 0.f, 0.f, 0.f};
        for (int ksl = 0; ksl < splitK; ++ksl) {
            const float4 pv =
                *(const float4*)&P[((size_t)ksl * TDIM + tok) * EDIM + lane * 4];
            a[0] += pv.x; a[1] += pv.y; a[2] += pv.z; a[3] += pv.w;
        }
        float v[4], s[4];
#pragma unroll
        for (int j = 0; j < 4; ++j) {
            v[j] = 1.f / (1.f + expf(-a[j]));
            s[j] = v[j] + bb[j];
        }
        float t1 = s[0], t2 = -FLT_MAX;
#pragma unroll
        for (int j = 1; j < 4; ++j) {
            if (s[j] > t1) { t2 = t1; t1 = s[j]; }
            else if (s[j] > t2) t2 = s[j];
        }
#pragma unroll
        for (int d = 1; d < 8; d <<= 1) {
            float o1 = __shfl_xor(t1, d);
            float o2 = __shfl_xor(t2, d);
            float n1 = fmaxf(t1, o1);
            float n2 = fmaxf(fminf(t1, o1), fmaxf(t2, o2));
            t1 = n1; t2 = n2;
        }
        const float gsc = t1 + t2;
        float gs[8];
#pragma unroll
        for (int q = 0; q < 8; ++q) gs[q] = __shfl(gsc, q * 8);
        int gmask = 0;
#pragma unroll
        for (int it = 0; it < 4; ++it) {
            float bvv = -FLT_MAX; int bg = 0;
#pragma unroll
            for (int q = 0; q < 8; ++q) {
                const bool avail = ((gmask >> q) & 1) == 0;
                if (avail && gs[q] > bvv) { bvv = gs[q]; bg = q; }
            }
            gmask |= (1 << bg);
        }
        if (((gmask >> g) & 1) == 0) { s[0] = 0.f; s[1] = 0.f; s[2] = 0.f; s[3] = 0.f; }

        float wk[8]; int ik[8]; float wsum = 0.f;
#pragma unroll
        for (int it = 0; it < 8; ++it) {
            float bvv = s[0]; int bi = lane * 4; float bs = v[0];
#pragma unroll
            for (int j = 1; j < 4; ++j)
                if (s[j] > bvv) { bvv = s[j]; bi = lane * 4 + j; bs = v[j]; }
#pragma unroll
            for (int d = 1; d < 64; d <<= 1) {
                float ov = __shfl_xor(bvv, d);
                int   oi = __shfl_xor(bi, d);
                float os = __shfl_xor(bs, d);
                if (ov > bvv || (ov == bvv && oi < bi)) { bvv = ov; bi = oi; bs = os; }
            }
            wk[it] = bs; ik[it] = bi; wsum += bs;
#pragma unroll
            for (int j = 0; j < 4; ++j)
                if (bi == lane * 4 + j) s[j] = -FLT_MAX;
        }
        const float den = wsum + 1e-20f;
        if (lane == 0) {
#pragma unroll
            for (int q = 0; q < 8; ++q) {
                out[(size_t)tok * 8 + q] = wk[q] / den * 2.5f;
                out[(size_t)TDIM * 8 + (size_t)tok * 8 + q] = (float)ik[q];
            }
        }
    }
}

extern "C" void kernel_launch(void* const* d_in, const int* in_sizes, int n_in,
                              void* d_out, int out_size, void* d_ws, size_t ws_size,
                              hipStream_t stream)
{
    (void)in_sizes; (void)n_in; (void)out_size;
    const float* x    = (const float*)d_in[0];
    const float* kern = (const float*)d_in[1];
    const float* bias = (const float*)d_in[2];
    float* out = (float*)d_out;

    const size_t planeBytes = (size_t)EDIM * DDIM * sizeof(_Float16);
    int splitK = 4;
    while (splitK > 1 &&
           (size_t)splitK * TDIM * EDIM * 4 + 2 * planeBytes > ws_size)
        splitK >>= 1;

    float* P = (float*)d_ws;
    _Float16* Wt0 = (_Float16*)((char*)d_ws + (size_t)splitK * TDIM * EDIM * 4);
    _Float16* Wt1 = Wt0 + (size_t)EDIM * DDIM;

    convert_w<<<dim3(DDIM / 64, EDIM / 64), 256, 0, stream>>>(kern, Wt0, Wt1);
    gemm_mfma<<<(TDIM / 128) * 2 * splitK, 256, 0, stream>>>(
        x, Wt0, Wt1, P, splitK, DDIM / splitK);
    route_kernel<<<TDIM / 32, 256, 0, stream>>>(P, bias, out, splitK);
}

// Round 7
// 182.426 us; speedup vs baseline: 1.0092x; 1.0092x over previous
//
#include <hip/hip_runtime.h>
#include <math.h>
#include <float.h>

// DeepSeek V3 router, round 7.
// Single-accumulator split-fp16 MFMA GEMM. Three passes into ONE acc via
// exact power-of-2 operand rescales (v_pk_mul_f16, in-register):
//   pass1: a0*b0                 (a0=fp16(x),        b0=fp16(256w))
//   pass2: (a1*2^-6)*(b0*2^-5)   (a1=fp16(res_x*2048))  == res_x*256w
//   pass3: (a0*2^-5)*b3          (b3=fp16(res_w256*32)) == fp16(x)*res_w256
// All scaled operands normal-range except flush-loss-bounded <=~1e-7 logit.
// Acc regs 128->64 unlocks 8-wave blocks (512thr, wave-tile 32x64, ~110 VGPR)
// -> 4 waves/SIMD at 2 blocks/CU (LDS 64KB). Raw-barrier loop, counted DMA.

#define TDIM 8192
#define DDIM 7168
#define EDIM 256

typedef _Float16 h8 __attribute__((ext_vector_type(8)));
typedef float f4 __attribute__((ext_vector_type(4)));

typedef const __attribute__((address_space(1))) void* gas_t;
typedef __attribute__((address_space(3))) void* las_t;

// ---------------- K1: W -> 2 transposed fp16 planes [E][K] ----------------
// plane0 = fp16(256w); plane1 = fp16((256w - plane0) * 32)
__global__ __launch_bounds__(256)
void convert_w(const float* __restrict__ W,
               _Float16* __restrict__ Wt0, _Float16* __restrict__ Wt3)
{
    __shared__ _Float16 l0[64][80];
    __shared__ _Float16 l1[64][80];
    const int t = threadIdx.x;
    const int kt = blockIdx.x * 64;
    const int et = blockIdx.y * 64;
#pragma unroll
    for (int i = 0; i < 16; ++i) {
        const int kr = (t >> 6) * 16 + i;
        const int ec = t & 63;
        const float w = W[(size_t)(kt + kr) * EDIM + et + ec] * 256.f;
        const _Float16 h0 = (_Float16)w;
        const _Float16 h1 = (_Float16)((w - (float)h0) * 32.f);
        l0[ec][kr] = h0;
        l1[ec][kr] = h1;
    }
    __syncthreads();
#pragma unroll
    for (int j = 0; j < 2; ++j) {
        const int er = t >> 2;
        const int kc = ((t & 3) + 4 * j) * 8;
        const uint4 v0 = *(const uint4*)&l0[er][kc];
        const uint4 v1 = *(const uint4*)&l1[er][kc];
        *(uint4*)&Wt0[(size_t)(et + er) * DDIM + kt + kc] = v0;
        *(uint4*)&Wt3[(size_t)(et + er) * DDIM + kt + kc] = v1;
    }
}

// ---------------- K2: single-acc split-fp16 MFMA GEMM ----------------
// LDS: 16B slot s of row r holds original granule s ^ ((r>>2)&3).
__global__ __launch_bounds__(512, 4)
void gemm_mfma(const float* __restrict__ X,
               const _Float16* __restrict__ Wt0,
               const _Float16* __restrict__ Wt3,
               float* __restrict__ P,
               int splitK, int kLen)
{
    __shared__ _Float16 sA[2][2][128][32];  // 32 KB
    __shared__ _Float16 sB[2][2][128][32];  // 32 KB

    const int t    = threadIdx.x;
    const int lane = t & 63;
    const int w    = t >> 6;              // wave 0..7

    const int cpx = gridDim.x >> 3;
    const int L   = (blockIdx.x & 7) * cpx + (blockIdx.x >> 3);
    const int nb  = L & 1;
    const int r1  = L >> 1;
    const int ks  = r1 % splitK;
    const int mb  = r1 / splitK;
    const int m0  = mb * 128;
    const int e0  = nb * 128;
    const int kbeg = ks * kLen;
    const int ntiles = kLen >> 5;

    f4 acc[2][4];
#pragma unroll
    for (int i = 0; i < 2; ++i)
#pragma unroll
        for (int j = 0; j < 4; ++j) acc[i][j] = (f4)0.f;

    // ---- A staging: thread -> row t>>2, granule t&3 (8 floats) ----
    const int rowA  = t >> 2;
    const int g0    = t & 3;
    const float* xg = X + (size_t)(m0 + rowA) * DDIM + kbeg + g0 * 8;
    const int slotA = (g0 ^ ((rowA >> 2) & 3)) * 8;   // halfs

    // ---- B staging (DMA): wave w -> plane w&1, rows (w>>1)*16 + {0,64} ----
    const _Float16* bsrc[2];
    {
        const int gsw = ((lane & 3) ^ ((lane >> 4) & 3)) * 8;
        const _Float16* wp = (w & 1) ? Wt3 : Wt0;
#pragma unroll
        for (int i = 0; i < 2; ++i) {
            const int rb = (w >> 1) * 16 + i * 64;
            bsrc[i] = wp + (size_t)(e0 + rb + (lane >> 2)) * DDIM + kbeg + gsw;
        }
    }

    float4 va0, va1;

#define LOADA(kb)                                                             \
    {                                                                         \
        va0 = *(const float4*)(xg + (kb));                                    \
        va1 = *(const float4*)(xg + (kb) + 4);                                \
    }

#define DMAB(buf, kb)                                                         \
    {                                                                         \
        _Pragma("unroll")                                                     \
        for (int i = 0; i < 2; ++i)                                           \
            __builtin_amdgcn_global_load_lds(                                 \
                (gas_t)(bsrc[i] + (kb)),                                      \
                (las_t)&sB[buf][w & 1][(w >> 1) * 16 + i * 64][0],            \
                16, 0, 0);                                                    \
    }

#define WRITEA(buf)                                                           \
    {                                                                         \
        h8 p0, p1;                                                            \
        const float xv[8] = {va0.x, va0.y, va0.z, va0.w,                      \
                             va1.x, va1.y, va1.z, va1.w};                     \
        _Pragma("unroll")                                                     \
        for (int j = 0; j < 8; ++j) {                                         \
            const _Float16 h0 = (_Float16)xv[j];                              \
            p0[j] = h0;                                                       \
            p1[j] = (_Float16)((xv[j] - (float)h0) * 2048.f);                 \
        }                                                                     \
        *(h8*)&sA[buf][0][rowA][slotA] = p0;                                  \
        *(h8*)&sA[buf][1][rowA][slotA] = p1;                                  \
    }

    // prologue
    LOADA(0);
    DMAB(0, 0);
    WRITEA(0);                 // waits va (vmcnt(2)), DMAs stay in flight
    asm volatile("s_waitcnt lgkmcnt(0)" ::: "memory");
    __builtin_amdgcn_s_barrier();

    const int fr  = (w & 3) * 32 + (lane & 15);     // A rows (wave m-tile 32)
    const int fc  = (w >> 2) * 64 + (lane & 15);    // B rows (wave n-tile 64)
    const int kqs = (((lane >> 4) ^ (lane >> 2)) & 3) << 3;
    const _Float16 S5 = (_Float16)0.03125f;     // 2^-5
    const _Float16 S6 = (_Float16)0.015625f;    // 2^-6

    for (int tile = 0; tile < ntiles; ++tile) {
        const int cur = tile & 1;
        const int nxt = cur ^ 1;
        // B DMA for cur (issued a full step ago) must be complete
        asm volatile("s_waitcnt vmcnt(0)" ::: "memory");

        const bool hn = (tile + 1) < ntiles;
        if (hn) {
            LOADA((tile + 1) * 32);     // va first (oldest)
            DMAB(nxt, (tile + 1) * 32); // DMAs newest -> survive va wait
        }

        h8 a0[2], a1[2], b0[4], b3[4];
#pragma unroll
        for (int h = 0; h < 2; ++h) {
            a0[h] = *(const h8*)&sA[cur][0][fr + h * 16][kqs];
            a1[h] = *(const h8*)&sA[cur][1][fr + h * 16][kqs];
        }
#pragma unroll
        for (int f = 0; f < 4; ++f) {
            b0[f] = *(const h8*)&sB[cur][0][fc + f * 16][kqs];
            b3[f] = *(const h8*)&sB[cur][1][fc + f * 16][kqs];
        }

        __builtin_amdgcn_s_setprio(1);
#pragma unroll
        for (int h = 0; h < 2; ++h)
#pragma unroll
            for (int f = 0; f < 4; ++f)
                acc[h][f] = __builtin_amdgcn_mfma_f32_16x16x32_f16(
                    a0[h], b0[f], acc[h][f], 0, 0, 0);
#pragma unroll
        for (int f = 0; f < 4; ++f)
#pragma unroll
            for (int j = 0; j < 8; ++j) b0[f][j] *= S5;
#pragma unroll
        for (int h = 0; h < 2; ++h)
#pragma unroll
            for (int j = 0; j < 8; ++j) a1[h][j] *= S6;
#pragma unroll
        for (int h = 0; h < 2; ++h)
#pragma unroll
            for (int f = 0; f < 4; ++f)
                acc[h][f] = __builtin_amdgcn_mfma_f32_16x16x32_f16(
                    a1[h], b0[f], acc[h][f], 0, 0, 0);
#pragma unroll
        for (int h = 0; h < 2; ++h)
#pragma unroll
            for (int j = 0; j < 8; ++j) a0[h][j] *= S5;
#pragma unroll
        for (int h = 0; h < 2; ++h)
#pragma unroll
            for (int f = 0; f < 4; ++f)
                acc[h][f] = __builtin_amdgcn_mfma_f32_16x16x32_f16(
                    a0[h], b3[f], acc[h][f], 0, 0, 0);
        __builtin_amdgcn_s_setprio(0);

        if (hn) WRITEA(nxt);           // waits va via vmcnt(2): DMAs in flight
        asm volatile("s_waitcnt lgkmcnt(0)" ::: "memory");
        __builtin_amdgcn_s_barrier();
    }

    // epilogue: logit = acc / 256
    const float s0 = 1.f / 256.f;
#pragma unroll
    for (int h = 0; h < 2; ++h)
#pragma unroll
        for (int f = 0; f < 4; ++f) {
            const int gr = m0 + (w & 3) * 32 + h * 16 + (lane >> 4) * 4;
            const int gc = e0 + (w >> 2) * 64 + f * 16 + (lane & 15);
#pragma unroll
            for (int r = 0; r < 4; ++r)
                P[((size_t)ks * TDIM + gr + r) * EDIM + gc] = acc[h][f][r] * s0;
        }
}

// ---------------- K3: reduce + sigmoid + grouped top-k route ----------------
__global__ __launch_bounds__(256, 4)
void route_kernel(const float* __restrict__ P,
                  const float* __restrict__ B,
                  float* __restrict__ out,
                  int splitK)
{
    const int t    = threadIdx.x;
    const int lane = t & 63;
    const int wid  = t >> 6;
    const int tok0 = blockIdx.x * 32 + wid * 8;

    const float4 bv4 = *(const float4*)&B[lane * 4];
    const float bb[4] = {bv4.x, bv4.y, bv4.z, bv4.w};
    const int g = lane >> 3;

#pragma unroll
    for (int i = 0; i < 8; ++i) {
        const int tok = tok0 + i;
        float a[4] = {0.f, 0.f, 0.f, 0.f};
        for (int ksl = 0; ksl < splitK; ++ksl) {
            const float4 pv =
                *(const float4*)&P[((size_t)ksl * TDIM + tok) * EDIM + lane * 4];
            a[0] += pv.x; a[1] += pv.y; a[2] += pv.z; a[3] += pv.w;
        }
        float v[4], s[4];
#pragma unroll
        for (int j = 0; j < 4; ++j) {
            v[j] = 1.f / (1.f + expf(-a[j]));
            s[j] = v[j] + bb[j];
        }
        float t1 = s[0], t2 = -FLT_MAX;
#pragma unroll
        for (int j = 1; j < 4; ++j) {
            if (s[j] > t1) { t2 = t1; t1 = s[j]; }
            else if (s[j] > t2) t2 = s[j];
        }
#pragma unroll
        for (int d = 1; d < 8; d <<= 1) {
            float o1 = __shfl_xor(t1, d);
            float o2 = __shfl_xor(t2, d);
            float n1 = fmaxf(t1, o1);
            float n2 = fmaxf(fminf(t1, o1), fmaxf(t2, o2));
            t1 = n1; t2 = n2;
        }
        const float gsc = t1 + t2;
        float gs[8];
#pragma unroll
        for (int q = 0; q < 8; ++q) gs[q] = __shfl(gsc, q * 8);
        int gmask = 0;
#pragma unroll
        for (int it = 0; it < 4; ++it) {
            float bvv = -FLT_MAX; int bg = 0;
#pragma unroll
            for (int q = 0; q < 8; ++q) {
                const bool avail = ((gmask >> q) & 1) == 0;
                if (avail && gs[q] > bvv) { bvv = gs[q]; bg = q; }
            }
            gmask |= (1 << bg);
        }
        if (((gmask >> g) & 1) == 0) { s[0] = 0.f; s[1] = 0.f; s[2] = 0.f; s[3] = 0.f; }

        float wk[8]; int ik[8]; float wsum = 0.f;
#pragma unroll
        for (int it = 0; it < 8; ++it) {
            float bvv = s[0]; int bi = lane * 4; float bs = v[0];
#pragma unroll
            for (int j = 1; j < 4; ++j)
                if (s[j] > bvv) { bvv = s[j]; bi = lane * 4 + j; bs = v[j]; }
#pragma unroll
            for (int d = 1; d < 64; d <<= 1) {
                float ov = __shfl_xor(bvv, d);
                int   oi = __shfl_xor(bi, d);
                float os = __shfl_xor(bs, d);
                if (ov > bvv || (ov == bvv && oi < bi)) { bvv = ov; bi = oi; bs = os; }
            }
            wk[it] = bs; ik[it] = bi; wsum += bs;
#pragma unroll
            for (int j = 0; j < 4; ++j)
                if (bi == lane * 4 + j) s[j] = -FLT_MAX;
        }
        const float den = wsum + 1e-20f;
        if (lane == 0) {
#pragma unroll
            for (int q = 0; q < 8; ++q) {
                out[(size_t)tok * 8 + q] = wk[q] / den * 2.5f;
                out[(size_t)TDIM * 8 + (size_t)tok * 8 + q] = (float)ik[q];
            }
        }
    }
}

extern "C" void kernel_launch(void* const* d_in, const int* in_sizes, int n_in,
                              void* d_out, int out_size, void* d_ws, size_t ws_size,
                              hipStream_t stream)
{
    (void)in_sizes; (void)n_in; (void)out_size;
    const float* x    = (const float*)d_in[0];
    const float* kern = (const float*)d_in[1];
    const float* bias = (const float*)d_in[2];
    float* out = (float*)d_out;

    const size_t planeBytes = (size_t)EDIM * DDIM * sizeof(_Float16);
    int splitK = 4;
    while (splitK > 1 &&
           (size_t)splitK * TDIM * EDIM * 4 + 2 * planeBytes > ws_size)
        splitK >>= 1;

    float* P = (float*)d_ws;
    _Float16* Wt0 = (_Float16*)((char*)d_ws + (size_t)splitK * TDIM * EDIM * 4);
    _Float16* Wt3 = Wt0 + (size_t)EDIM * DDIM;

    convert_w<<<dim3(DDIM / 64, EDIM / 64), 256, 0, stream>>>(kern, Wt0, Wt3);
    gemm_mfma<<<(TDIM / 128) * 2 * splitK, 512, 0, stream>>>(
        x, Wt0, Wt3, P, splitK, DDIM / splitK);
    route_kernel<<<TDIM / 32, 256, 0, stream>>>(P, bias, out, splitK);
}